// Round 2
// baseline (255.790 us; speedup 1.0000x reference)
//
#include <hip/hip_runtime.h>
#include <hip/hip_bf16.h>
#include <math.h>

// EdgeEmbedding, fully local + fully coalesced form.
//
// Structural identity: edge_vec[e] = pair_vec[p] * orient[e], orient = +-1,
// 2 edges per pair. *(+-1) is exact in fp32 and (v+v)/2 = v exactly, so each
// edge reconstructs pair_vec locally => no atomics / gather.
//
// All global I/O is staged through LDS so every global transaction is a
// contiguous per-lane float4 (or a contiguous dword for edge_length).
// LDS strides: s_vec stride 3, s_emb stride 9 (8 used + pad), s_attr stride 9
// -> all coprime-to-32 patterns = <=2-way bank aliasing (free on CDNA4).
//
// R0/R1 change: all output stores NON-TEMPORAL. 216 MB of write-once output
// has zero reuse; keep it out of the per-XCD L2s. nt vector stores use a
// clang ext_vector type (HIP's float4 class is rejected by the builtin).

#define TPB 256

typedef float f32x4 __attribute__((ext_vector_type(4)));

__global__ __launch_bounds__(TPB) void edge_kernel(const float* __restrict__ edge_vec,
                                                   const unsigned char* __restrict__ rev,
                                                   const float* __restrict__ coeffs,
                                                   float* __restrict__ out, int E) {
    __shared__ float s_vec[TPB * 3];    // 3072 B
    __shared__ float s_emb[TPB * 9];    // 9216 B (stride 9, col 8 unused pad)
    __shared__ float s_attr[TPB * 9];   // 9216 B

    int t = threadIdx.x;
    long long e0 = (long long)blockIdx.x * TPB;   // first edge of this block
    long long e  = e0 + t;
    bool valid = e < E;

    // --- bool storage-width detect, per wave (first 4096 B of rev, L2-hot).
    // Any word > 1 => byte-packed numpy bools; else int32 storage.
    int shift;
    {
        const uint4* rw = (const uint4*)rev;
        unsigned bad = 0;
        int lane = t & 63;
#pragma unroll
        for (int k = 0; k < 4; k++) {
            uint4 w = rw[lane + 64 * k];
            bad |= (w.x > 1u) | (w.y > 1u) | (w.z > 1u) | (w.w > 1u);
        }
        shift = __any(bad) ? 0 : 2;
    }

    // --- stage edge_vec chunk: 192 float4 = 768 floats, fully coalesced
    {
        const float4* gvec = (const float4*)edge_vec;
        long long v4base = (long long)blockIdx.x * (TPB * 3 / 4);
        if (t < TPB * 3 / 4) {
            long long g4 = v4base + t;
            if (4 * g4 < 3LL * E) ((float4*)s_vec)[t] = gvec[g4];
        }
    }
    // per-edge reversed flag (guarded: int32 storage reads byte 4e)
    bool isrev = valid && (rev[(size_t)e << shift] != 0);
    __syncthreads();

    {
        float o = isrev ? -1.0f : 1.0f;
        float px = s_vec[3 * t + 0] * o;
        float py = s_vec[3 * t + 1] * o;
        float pz = s_vec[3 * t + 2] * o;

        float r = sqrtf(px * px + py * py + pz * pz);
        float rs = fmaxf(r, 1e-12f);

        // poly_cutoff p=6: 1 - 28 x^6 + 48 x^7 - 21 x^8, zero at x>=1
        float xr = r * 0.2f;                 // r / RC, RC=5
        float x3 = xr * xr * xr;
        float x6 = x3 * x3;
        float env = 1.0f - 28.0f * x6 + 48.0f * x6 * xr - 21.0f * x6 * xr * xr;
        env = (xr < 1.0f) ? env : 0.0f;

        float pref = 0.632455532034f / rs * env;   // sqrt(2/5)
#pragma unroll
        for (int j = 0; j < 8; j++)
            s_emb[9 * t + j] = pref * __sinf(coeffs[j] * xr);

        float ux = px / rs, uy = py / rs, uz = pz / rs;
        const float s3 = 1.73205080757f, s15 = 3.87298334621f, s5 = 2.2360679775f;
        float sh1 = s3 * ux, sh2 = s3 * uy, sh3 = s3 * uz;
        if (isrev) { sh1 = -sh1; sh2 = -sh2; sh3 = -sh3; }   // SH parity on l=1
        s_attr[9 * t + 0] = 1.0f;
        s_attr[9 * t + 1] = sh1;
        s_attr[9 * t + 2] = sh2;
        s_attr[9 * t + 3] = sh3;
        s_attr[9 * t + 4] = s15 * ux * uy;
        s_attr[9 * t + 5] = s15 * uy * uz;
        s_attr[9 * t + 6] = 0.5f * s5 * (3.0f * uz * uz - 1.0f);
        s_attr[9 * t + 7] = s15 * ux * uz;
        s_attr[9 * t + 8] = 0.5f * s15 * (ux * ux - uy * uy);

        // edge_length: contiguous dword store, already fully coalesced
        if (valid) __builtin_nontemporal_store(r, &out[e]);
    }
    __syncthreads();

    // --- cooperative coalesced float4 stores (non-temporal) ---
    f32x4* o4 = (f32x4*)out;

    // edge_embedding region: floats [E, 9E); block chunk = 2048 floats = 512 f4
    long long embStart4 = ((long long)E >> 2) + (long long)blockIdx.x * 512;
    long long embEnd4   = 9LL * E >> 2;
#pragma unroll
    for (int k = t; k < 512; k += TPB) {
        long long g4 = embStart4 + k;
        if (g4 < embEnd4) {
            int f0 = 4 * k;   // logical float index within block chunk (stride-8 layout)
            f32x4 v;
            v.x = s_emb[9 * ((f0 + 0) >> 3) + ((f0 + 0) & 7)];
            v.y = s_emb[9 * ((f0 + 1) >> 3) + ((f0 + 1) & 7)];
            v.z = s_emb[9 * ((f0 + 2) >> 3) + ((f0 + 2) & 7)];
            v.w = s_emb[9 * ((f0 + 3) >> 3) + ((f0 + 3) & 7)];
            __builtin_nontemporal_store(v, &o4[g4]);
        }
    }

    // edge_attr region: floats [9E, 18E); block chunk = 2304 floats = 576 f4
    long long attrStart4 = (9LL * E >> 2) + (long long)blockIdx.x * 576;
    long long attrEnd4   = 18LL * E >> 2;
#pragma unroll
    for (int k = t; k < 576; k += TPB) {
        long long g4 = attrStart4 + k;
        if (g4 < attrEnd4) {
            f32x4 v = ((f32x4*)s_attr)[k];
            __builtin_nontemporal_store(v, &o4[g4]);
        }
    }
}

extern "C" void kernel_launch(void* const* d_in, const int* in_sizes, int n_in,
                              void* d_out, int out_size, void* d_ws, size_t ws_size,
                              hipStream_t stream) {
    const float* edge_vec = (const float*)d_in[0];
    const float* coeffs   = (const float*)d_in[1];
    const unsigned char* rev = (const unsigned char*)d_in[3];

    int E = in_sizes[2];          // 2P edges
    float* out = (float*)d_out;

    int eblocks = (E + TPB - 1) / TPB;
    edge_kernel<<<eblocks, TPB, 0, stream>>>(edge_vec, rev, coeffs, out, E);
}